// Round 4
// baseline (345.551 us; speedup 1.0000x reference)
//
#include <hip/hip_runtime.h>

#define G 8
#define S 2048
#define DMODEL 1024
#define NE 8
#define TOKENS (G * S)

// ---------------------------------------------------------------------------
// Kernel A: gating logits + softmax + top-2 per token.
// One wave (64 threads) per block; each wave handles 8 consecutive tokens.
// W (1024x8 f32 = 32KB) is preloaded into 128 VGPRs per wave (float4 pairs),
// reused across the 8 tokens. x loads are lane-coalesced (d = lane + 64*c).
// ---------------------------------------------------------------------------
__global__ __launch_bounds__(64) void gate_topk_kernel(
    const float* __restrict__ x, const float* __restrict__ W,
    const float* __restrict__ bias,
    int* __restrict__ idx01, float* __restrict__ g0out,
    float* __restrict__ g1out) {
  const int lane = threadIdx.x;
  const int tok0 = blockIdx.x * 8;

  // Preload this lane's W slice: d = lane + 64*c, experts 0-3 (wa) / 4-7 (wb)
  const float4* W4 = (const float4*)W;
  float4 wa[16], wb[16];
#pragma unroll
  for (int c = 0; c < 16; ++c) {
    int d = lane + (c << 6);
    wa[c] = W4[d * 2];
    wb[c] = W4[d * 2 + 1];
  }
  float b[8];
#pragma unroll
  for (int e = 0; e < 8; ++e) b[e] = bias[e];

  for (int t = 0; t < 8; ++t) {
    const int tok = tok0 + t;
    const float* xp = x + (size_t)tok * DMODEL;
    float acc[8] = {0.f, 0.f, 0.f, 0.f, 0.f, 0.f, 0.f, 0.f};
#pragma unroll
    for (int c = 0; c < 16; ++c) {
      float xv = xp[lane + (c << 6)];
      acc[0] = fmaf(xv, wa[c].x, acc[0]);
      acc[1] = fmaf(xv, wa[c].y, acc[1]);
      acc[2] = fmaf(xv, wa[c].z, acc[2]);
      acc[3] = fmaf(xv, wa[c].w, acc[3]);
      acc[4] = fmaf(xv, wb[c].x, acc[4]);
      acc[5] = fmaf(xv, wb[c].y, acc[5]);
      acc[6] = fmaf(xv, wb[c].z, acc[6]);
      acc[7] = fmaf(xv, wb[c].w, acc[7]);
    }
    // 64-lane butterfly reduce for each of the 8 expert logits
#pragma unroll
    for (int e = 0; e < 8; ++e) {
      float v = acc[e];
#pragma unroll
      for (int off = 1; off < 64; off <<= 1) v += __shfl_xor(v, off);
      acc[e] = v + b[e];
    }
    if (lane == 0) {
      float m = acc[0];
#pragma unroll
      for (int e = 1; e < 8; ++e) m = fmaxf(m, acc[e]);
      float p[8], sum = 0.f;
#pragma unroll
      for (int e = 0; e < 8; ++e) {
        p[e] = __expf(acc[e] - m);
        sum += p[e];
      }
      // top-2 by logit (softmax is monotone); first-index wins on ties
      int i0 = 0;
      float best = acc[0];
#pragma unroll
      for (int e = 1; e < 8; ++e)
        if (acc[e] > best) { best = acc[e]; i0 = e; }
      int i1 = -1;
      float b1 = 0.f;
#pragma unroll
      for (int e = 0; e < 8; ++e) {
        if (e == i0) continue;
        if (i1 < 0 || acc[e] > b1) { b1 = acc[e]; i1 = e; }
      }
      float inv = 1.0f / sum;
      idx01[tok] = i0 | (i1 << 8);
      g0out[tok] = p[i0] * inv;
      g1out[tok] = p[i1] * inv;
    }
  }
}

// ---------------------------------------------------------------------------
// Kernel B: per-(group,expert) cumulative position along the sequence.
// CRITICAL reference semantics: cumsum is over axis=1 (S) with the k-dim
// SEPARATE — top-1 assignments and top-2 assignments to the same expert use
// INDEPENDENT counters. So: 4 packed uint64 counter words per thread:
//   a0/a1 = k=0 counts for experts 0-3 / 4-7 (8 x 16-bit fields total)
//   b0/b1 = k=1 counts for experts 0-3 / 4-7
// One block of 256 threads per group; thread t owns tokens t*8..t*8+7.
// Inclusive scan: shfl_up within wave, LDS for cross-wave offsets.
// ---------------------------------------------------------------------------
__global__ __launch_bounds__(256) void scan_kernel(
    const int* __restrict__ idx01, int* __restrict__ pos0,
    int* __restrict__ pos1) {
  const int g = blockIdx.x;
  const int t = threadIdx.x;
  const int lane = t & 63;
  const int wave = t >> 6;
  const int base = g * S + t * 8;

  int loc[8];
  unsigned long long a0 = 0ULL, a1 = 0ULL, b0 = 0ULL, b1 = 0ULL;
#pragma unroll
  for (int i = 0; i < 8; ++i) {
    int v = idx01[base + i];
    loc[i] = v;
    int i0 = v & 0xFF, i1 = (v >> 8) & 0xFF;
    if (i0 < 4) a0 += 1ULL << (16 * i0); else a1 += 1ULL << (16 * (i0 & 3));
    if (i1 < 4) b0 += 1ULL << (16 * i1); else b1 += 1ULL << (16 * (i1 & 3));
  }
  const unsigned long long la0 = a0, la1 = a1, lb0 = b0, lb1 = b1;

  // inclusive wave scan (per-lane prefix sums of the 4 packed words)
#pragma unroll
  for (int off = 1; off < 64; off <<= 1) {
    unsigned long long u0 = __shfl_up(a0, (unsigned)off);
    unsigned long long u1 = __shfl_up(a1, (unsigned)off);
    unsigned long long u2 = __shfl_up(b0, (unsigned)off);
    unsigned long long u3 = __shfl_up(b1, (unsigned)off);
    if (lane >= off) { a0 += u0; a1 += u1; b0 += u2; b1 += u3; }
  }

  __shared__ unsigned long long wt[4][4];  // [wave][word]
  if (lane == 63) {
    wt[wave][0] = a0; wt[wave][1] = a1; wt[wave][2] = b0; wt[wave][3] = b1;
  }
  __syncthreads();
  for (int w = 0; w < wave; ++w) {
    a0 += wt[w][0]; a1 += wt[w][1]; b0 += wt[w][2]; b1 += wt[w][3];
  }

  // exclusive prefix for this thread
  a0 -= la0; a1 -= la1; b0 -= lb0; b1 -= lb1;

  // replay own tokens in order
#pragma unroll
  for (int i = 0; i < 8; ++i) {
    int v = loc[i];
    int i0 = v & 0xFF, i1 = (v >> 8) & 0xFF;
    int p0, p1;
    {
      int sh = 16 * (i0 & 3);
      if (i0 < 4) { p0 = (int)((a0 >> sh) & 0xFFFF) + 1; a0 += 1ULL << sh; }
      else        { p0 = (int)((a1 >> sh) & 0xFFFF) + 1; a1 += 1ULL << sh; }
    }
    {
      int sh = 16 * (i1 & 3);
      if (i1 < 4) { p1 = (int)((b0 >> sh) & 0xFFFF) + 1; b0 += 1ULL << sh; }
      else        { p1 = (int)((b1 >> sh) & 0xFFFF) + 1; b1 += 1ULL << sh; }
    }
    pos0[base + i] = p0;
    pos1[base + i] = p1;
  }
}

// ---------------------------------------------------------------------------
// Kernel C: dense fill of combine_tensor and dispatch_mask.
// One wave per output row (g,s,e); 255 slots per row, written once each.
// Row value nonzero only at slot = pos-1 when the token picked expert e and
// pos <= slots (capacity check: pos < 256 <=> pos-1 in [0,255)).
// ---------------------------------------------------------------------------
__global__ __launch_bounds__(256) void fill_kernel(
    const int* __restrict__ idx01, const int* __restrict__ pos0,
    const int* __restrict__ pos1, const float* __restrict__ g0,
    const float* __restrict__ g1, float* __restrict__ combine,
    float* __restrict__ dispatch, int slots) {
  const int tid = blockIdx.x * 256 + threadIdx.x;
  const int wid = tid >> 6;   // row index = (g*S + s)*NE + e
  const int lane = tid & 63;
  const int e = wid & 7;
  const int tok = wid >> 3;

  const int v = idx01[tok];
  const int i0 = v & 0xFF, i1 = (v >> 8) & 0xFF;
  int target = -1;
  float gate = 0.f;
  if (e == i0) {
    int p = pos0[tok];
    if (p <= slots) { target = p - 1; gate = g0[tok]; }
  } else if (e == i1) {
    int p = pos1[tok];
    if (p <= slots) { target = p - 1; gate = g1[tok]; }
  }
  const bool hit_valid = (gate != 0.f);

  const size_t base = (size_t)wid * (size_t)slots;
#pragma unroll
  for (int c = 0; c < 4; ++c) {
    int slot = lane + (c << 6);
    if (slot < slots) {
      bool hit = (slot == target);
      combine[base + slot] = hit ? gate : 0.f;
      dispatch[base + slot] = (hit && hit_valid) ? 1.f : 0.f;
    }
  }
}

// ---------------------------------------------------------------------------
extern "C" void kernel_launch(void* const* d_in, const int* in_sizes, int n_in,
                              void* d_out, int out_size, void* d_ws,
                              size_t ws_size, hipStream_t stream) {
  const float* x = (const float*)d_in[0];
  const float* W = (const float*)d_in[1];
  const float* bias = (const float*)d_in[2];
  // d_in[3] = expert_capacity; output slot count is derivable from out_size.

  float* out = (float*)d_out;
  const int rows = TOKENS * NE;                 // 131072
  const int slots = out_size / (2 * rows);      // 255 (= capacity - 1)
  float* combine = out;
  float* dispatch = out + (size_t)(out_size / 2);

  char* ws = (char*)d_ws;
  int* idx01 = (int*)(ws + 0);
  float* g0 = (float*)(ws + TOKENS * 4);
  float* g1 = (float*)(ws + TOKENS * 8);
  int* pos0 = (int*)(ws + TOKENS * 12);
  int* pos1 = (int*)(ws + TOKENS * 16);

  // A: 8 tokens per wave, 1 wave per block -> 2048 blocks (8 blocks/CU)
  gate_topk_kernel<<<TOKENS / 8, 64, 0, stream>>>(x, W, bias, idx01, g0, g1);
  // B: one block per group
  scan_kernel<<<G, 256, 0, stream>>>(idx01, pos0, pos1);
  // C: one wave per row -> rows*64 threads
  fill_kernel<<<(rows * 64) / 256, 256, 0, stream>>>(idx01, pos0, pos1, g0, g1,
                                                     combine, dispatch, slots);
}

// Round 5
// 335.043 us; speedup vs baseline: 1.0314x; 1.0314x over previous
//
#include <hip/hip_runtime.h>

#define G 8
#define S 2048
#define DMODEL 1024
#define NE 8
#define TOKENS (G * S)

// ---------------------------------------------------------------------------
// Kernel A: gating logits + softmax + top-2 per token.
// One wave per block; each wave handles 8 consecutive tokens.
// W (1024x8 f32 = 32KB) preloaded into 128 VGPRs, reused across the 8 tokens.
// x loads are float4 (16B/lane, G13): lane's chunk covers d = 4*(lane+64c)+j.
// ---------------------------------------------------------------------------
__global__ __launch_bounds__(64) void gate_topk_kernel(
    const float* __restrict__ x, const float* __restrict__ W,
    const float* __restrict__ bias,
    int* __restrict__ idx01, float* __restrict__ g0out,
    float* __restrict__ g1out) {
  const int lane = threadIdx.x;
  const int tok0 = blockIdx.x * 8;

  // W4[d*2] = experts 0-3 of row d; W4[d*2+1] = experts 4-7.
  const float4* W4 = (const float4*)W;
  float4 wa[4][4], wb[4][4];
#pragma unroll
  for (int c = 0; c < 4; ++c) {
#pragma unroll
    for (int j = 0; j < 4; ++j) {
      int d = 4 * (lane + (c << 6)) + j;
      wa[c][j] = W4[d * 2];
      wb[c][j] = W4[d * 2 + 1];
    }
  }
  float b[8];
#pragma unroll
  for (int e = 0; e < 8; ++e) b[e] = bias[e];

  for (int t = 0; t < 8; ++t) {
    const int tok = tok0 + t;
    const float4* xp = (const float4*)(x + (size_t)tok * DMODEL);
    float acc[8] = {0.f, 0.f, 0.f, 0.f, 0.f, 0.f, 0.f, 0.f};
#pragma unroll
    for (int c = 0; c < 4; ++c) {
      float4 xv = xp[lane + (c << 6)];
      const float xs[4] = {xv.x, xv.y, xv.z, xv.w};  // compile-time indexed
#pragma unroll
      for (int j = 0; j < 4; ++j) {
        float s = xs[j];
        acc[0] = fmaf(s, wa[c][j].x, acc[0]);
        acc[1] = fmaf(s, wa[c][j].y, acc[1]);
        acc[2] = fmaf(s, wa[c][j].z, acc[2]);
        acc[3] = fmaf(s, wa[c][j].w, acc[3]);
        acc[4] = fmaf(s, wb[c][j].x, acc[4]);
        acc[5] = fmaf(s, wb[c][j].y, acc[5]);
        acc[6] = fmaf(s, wb[c][j].z, acc[6]);
        acc[7] = fmaf(s, wb[c][j].w, acc[7]);
      }
    }
    // 64-lane butterfly reduce for each of the 8 expert logits (ILP=8)
#pragma unroll
    for (int e = 0; e < 8; ++e) {
      float v = acc[e];
#pragma unroll
      for (int off = 1; off < 64; off <<= 1) v += __shfl_xor(v, off);
      acc[e] = v + b[e];
    }
    if (lane == 0) {
      float m = acc[0];
#pragma unroll
      for (int e = 1; e < 8; ++e) m = fmaxf(m, acc[e]);
      float p[8], sum = 0.f;
#pragma unroll
      for (int e = 0; e < 8; ++e) {
        p[e] = __expf(acc[e] - m);
        sum += p[e];
      }
      // top-2 by logit (softmax monotone); first-index wins ties
      int i0 = 0;
      float best = acc[0];
#pragma unroll
      for (int e = 1; e < 8; ++e)
        if (acc[e] > best) { best = acc[e]; i0 = e; }
      int i1 = -1;
      float b1 = 0.f;
#pragma unroll
      for (int e = 0; e < 8; ++e) {
        if (e == i0) continue;
        if (i1 < 0 || acc[e] > b1) { b1 = acc[e]; i1 = e; }
      }
      float inv = 1.0f / sum;
      idx01[tok] = i0 | (i1 << 8);
      g0out[tok] = p[i0] * inv;
      g1out[tok] = p[i1] * inv;
    }
  }
}

// ---------------------------------------------------------------------------
// Kernel B: k-separate cumsum scan + per-ROW meta emission.
// Reference semantics: cumsum over axis=1 (S) with the k-dim SEPARATE —
// top-1 and top-2 assignments to the same expert use INDEPENDENT counters.
// 4 packed uint64 words: a0/a1 = k=0 experts 0-3/4-7; b0/b1 = k=1.
// After the scan, each thread writes meta[row] = {target_slot, gate_bits}
// for all 8 expert-rows of each of its 8 tokens (64 int2 = 512B contiguous).
// target = -1 when the row has no valid assignment.
// ---------------------------------------------------------------------------
__global__ __launch_bounds__(256) void scan_meta_kernel(
    const int* __restrict__ idx01, const float* __restrict__ g0,
    const float* __restrict__ g1, int2* __restrict__ meta, int slots) {
  const int g = blockIdx.x;
  const int t = threadIdx.x;
  const int lane = t & 63;
  const int wave = t >> 6;
  const int base = g * S + t * 8;

  int loc[8];
  unsigned long long a0 = 0ULL, a1 = 0ULL, b0 = 0ULL, b1 = 0ULL;
#pragma unroll
  for (int i = 0; i < 8; ++i) {
    int v = idx01[base + i];
    loc[i] = v;
    int i0 = v & 0xFF, i1 = (v >> 8) & 0xFF;
    if (i0 < 4) a0 += 1ULL << (16 * i0); else a1 += 1ULL << (16 * (i0 & 3));
    if (i1 < 4) b0 += 1ULL << (16 * i1); else b1 += 1ULL << (16 * (i1 & 3));
  }
  const unsigned long long la0 = a0, la1 = a1, lb0 = b0, lb1 = b1;

#pragma unroll
  for (int off = 1; off < 64; off <<= 1) {
    unsigned long long u0 = __shfl_up(a0, (unsigned)off);
    unsigned long long u1 = __shfl_up(a1, (unsigned)off);
    unsigned long long u2 = __shfl_up(b0, (unsigned)off);
    unsigned long long u3 = __shfl_up(b1, (unsigned)off);
    if (lane >= off) { a0 += u0; a1 += u1; b0 += u2; b1 += u3; }
  }

  __shared__ unsigned long long wt[4][4];
  if (lane == 63) {
    wt[wave][0] = a0; wt[wave][1] = a1; wt[wave][2] = b0; wt[wave][3] = b1;
  }
  __syncthreads();
  for (int w = 0; w < wave; ++w) {
    a0 += wt[w][0]; a1 += wt[w][1]; b0 += wt[w][2]; b1 += wt[w][3];
  }

  a0 -= la0; a1 -= la1; b0 -= lb0; b1 -= lb1;  // exclusive prefix

#pragma unroll
  for (int i = 0; i < 8; ++i) {
    const int tok = base + i;
    int v = loc[i];
    int i0 = v & 0xFF, i1 = (v >> 8) & 0xFF;
    int p0, p1;
    {
      int sh = 16 * (i0 & 3);
      if (i0 < 4) { p0 = (int)((a0 >> sh) & 0xFFFF) + 1; a0 += 1ULL << sh; }
      else        { p0 = (int)((a1 >> sh) & 0xFFFF) + 1; a1 += 1ULL << sh; }
    }
    {
      int sh = 16 * (i1 & 3);
      if (i1 < 4) { p1 = (int)((b0 >> sh) & 0xFFFF) + 1; b0 += 1ULL << sh; }
      else        { p1 = (int)((b1 >> sh) & 0xFFFF) + 1; b1 += 1ULL << sh; }
    }
    const float G0 = g0[tok], G1 = g1[tok];
    int2* mrow = meta + (size_t)tok * NE;
#pragma unroll
    for (int e = 0; e < 8; ++e) {  // static indexing only (rule #20)
      int tgt = -1;
      float gv = 0.f;
      if (e == i0) {
        if (p0 <= slots) { tgt = p0 - 1; gv = G0; }
      } else if (e == i1) {
        if (p1 <= slots) { tgt = p1 - 1; gv = G1; }
      }
      mrow[e] = make_int2(tgt, __float_as_int(gv));
    }
  }
}

// ---------------------------------------------------------------------------
// Kernel C: flat float4 dense fill of combine_tensor + dispatch_mask.
// Each thread owns 4 consecutive dwords of the combine stream (16B/lane,
// dwordx4 stores, G13) and derives the dispatch chunk from it. Row index via
// exact magic-div by 255 (slots). Meta loads are L1-broadcast (64 consecutive
// chunks share a row). Grid-stride, 2048 blocks (G11).
// ---------------------------------------------------------------------------
__global__ __launch_bounds__(256) void fill_kernel(
    const int2* __restrict__ meta, float* __restrict__ combine,
    float* __restrict__ dispatch, int nchunks, int total_rows, int slots) {
  const int stride = gridDim.x * 256;
  for (int idx = blockIdx.x * 256 + threadIdx.x; idx < nchunks; idx += stride) {
    const unsigned f = (unsigned)idx * 4u;
    // row = f / slots (slots==255: exact magic divide)
    const unsigned row = __umulhi(f, 0x80808081u) >> 7;
    const int sb = (int)(f - row * 255u);
    const int2 mA = meta[row];
    unsigned rB = row + 1u;
    if ((int)rB >= total_rows) rB = row;  // safety clamp (dead for this shape)
    const int2 mB = meta[rB];
    const int ta = mA.x, tb = mB.x;
    const float ga = __int_as_float(mA.y), gb = __int_as_float(mB.y);

    float4 cv;
    {
      int s0 = sb + 0;
      cv.x = (s0 < 255) ? ((s0 == ta) ? ga : 0.f) : ((s0 - 255 == tb) ? gb : 0.f);
      int s1 = sb + 1;
      cv.y = (s1 < 255) ? ((s1 == ta) ? ga : 0.f) : ((s1 - 255 == tb) ? gb : 0.f);
      int s2 = sb + 2;
      cv.z = (s2 < 255) ? ((s2 == ta) ? ga : 0.f) : ((s2 - 255 == tb) ? gb : 0.f);
      int s3 = sb + 3;
      cv.w = (s3 < 255) ? ((s3 == ta) ? ga : 0.f) : ((s3 - 255 == tb) ? gb : 0.f);
    }
    ((float4*)combine)[idx] = cv;
    float4 dv;
    dv.x = (cv.x != 0.f) ? 1.f : 0.f;
    dv.y = (cv.y != 0.f) ? 1.f : 0.f;
    dv.z = (cv.z != 0.f) ? 1.f : 0.f;
    dv.w = (cv.w != 0.f) ? 1.f : 0.f;
    ((float4*)dispatch)[idx] = dv;
  }
}

// ---------------------------------------------------------------------------
extern "C" void kernel_launch(void* const* d_in, const int* in_sizes, int n_in,
                              void* d_out, int out_size, void* d_ws,
                              size_t ws_size, hipStream_t stream) {
  const float* x = (const float*)d_in[0];
  const float* W = (const float*)d_in[1];
  const float* bias = (const float*)d_in[2];

  float* out = (float*)d_out;
  const int rows = TOKENS * NE;             // 131072
  const int slots = out_size / (2 * rows);  // 255 (= capacity - 1)
  float* combine = out;
  float* dispatch = out + (size_t)(out_size / 2);

  char* ws = (char*)d_ws;
  int* idx01 = (int*)(ws + 0);
  float* g0 = (float*)(ws + TOKENS * 4);
  float* g1 = (float*)(ws + TOKENS * 8);
  int2* meta = (int2*)(ws + TOKENS * 12);   // rows * 8B = 1 MB

  const int ndwords = rows * slots;         // 33,423,360 (divisible by 4)
  const int nchunks = ndwords >> 2;

  gate_topk_kernel<<<TOKENS / 8, 64, 0, stream>>>(x, W, bias, idx01, g0, g1);
  scan_meta_kernel<<<G, 256, 0, stream>>>(idx01, g0, g1, meta, slots);
  fill_kernel<<<2048, 256, 0, stream>>>(meta, combine, dispatch, nchunks, rows,
                                        slots);
}